// Round 5
// baseline (154.031 us; speedup 1.0000x reference)
//
#include <hip/hip_runtime.h>
#include <hip/hip_bf16.h>

typedef __bf16 bf16;
typedef __bf16 bf16x4 __attribute__((ext_vector_type(4)));
typedef __bf16 bf16x8 __attribute__((ext_vector_type(8)));
typedef float floatx4 __attribute__((ext_vector_type(4)));

#define D_MODEL 512
#define NHEAD 8
#define HD 64
#define NB 2
#define NN 2048
#define BH (NB*NHEAD)
#define LOG2E 1.4426950408889634f

__device__ __forceinline__ float exp2_fast(float x) {
    float r;
    asm("v_exp_f32 %0, %1" : "=v"(r) : "v"(x));
    return r;
}

// ---------------- kernel 0: convert x,w fp32->bf16  (+ fused coordproj tail) ----------------
// blocks 0..2815: conversion; blocks 2816..2831: cp[b,h,n] = log2e * coords.rw
__global__ __launch_bounds__(256) void convxw(const float* __restrict__ x,
                                              const float* __restrict__ w,
                                              bf16* __restrict__ xb,
                                              bf16* __restrict__ wb,
                                              const float* __restrict__ coords,
                                              const float* __restrict__ rw,
                                              float* __restrict__ cp) {
    int blk = blockIdx.x;
    if (blk < 2816) {
        int idx = blk * 256 + threadIdx.x;
        const float* src; bf16* dst; int i4;
        if (idx < 524288) { src = x; dst = xb; i4 = idx; }
        else              { src = w; dst = wb; i4 = idx - 524288; }
        float4 v = *(const float4*)(src + (size_t)i4*4);
        bf16x4 o; o[0] = (bf16)v.x; o[1] = (bf16)v.y; o[2] = (bf16)v.z; o[3] = (bf16)v.w;
        *(bf16x4*)(dst + (size_t)i4*4) = o;
    } else {
        int idx = (blk - 2816) * 256 + threadIdx.x;   // 0..4095 over (b,n)
        int b = idx >> 11, n = idx & 2047;
        float c0 = coords[idx*3 + 0];
        float c1 = coords[idx*3 + 1];
        float c2 = coords[idx*3 + 2];
        for (int h = 0; h < NHEAD; h++) {
            float v = c0*rw[h*3+0] + c1*rw[h*3+1] + c2*rw[h*3+2];
            cp[(size_t)(b*NHEAD + h)*NN + n] = v * LOG2E;
        }
    }
}

// ---------------- kernel 2: QKV GEMM, C^T = W * X^T, register-prefetched ----------------
// Tile: 64 features x 128 rows, K=512. 768 blocks, 256 thr / 4 waves.
// Q pre-scaled by 0.125*log2e. V transposed via LDS -> vtb[bh][d][n].
__global__ __launch_bounds__(256, 4) void qkv_gemm(const bf16* __restrict__ xb,
                                                   const bf16* __restrict__ wb,
                                                   const float* __restrict__ bias,
                                                   bf16* __restrict__ qb,
                                                   bf16* __restrict__ kb,
                                                   bf16* __restrict__ vtb) {
    __shared__ bf16 smem[64*72 + 128*72];
    bf16 (*Ws)[72] = (bf16(*)[72])smem;
    bf16 (*Xs)[72] = (bf16(*)[72])(smem + 64*72);
    int t = threadIdx.x;
    int w = t >> 6, lane = t & 63, quad = lane >> 4, l15 = lane & 15;
    int blk = blockIdx.x;
    int bf = blk % 24, bm = blk / 24;
    int f0 = bf * 64, m0 = bm * 128;

    floatx4 acc[4][2] = {};
    int wrow = t >> 2, wcol = (t & 3) * 16;
    int xrow = t >> 1, xcol = (t & 1) * 32;

    const bf16* wsrc = wb + (size_t)(f0 + wrow)*D_MODEL + wcol;
    const bf16* xsrc = xb + (size_t)(m0 + xrow)*D_MODEL + xcol;

    // prefetch k0 = 0
    bf16x8 wr0 = *(const bf16x8*)wsrc;
    bf16x8 wr1 = *(const bf16x8*)(wsrc + 8);
    bf16x8 xr0 = *(const bf16x8*)xsrc;
    bf16x8 xr1 = *(const bf16x8*)(xsrc + 8);
    bf16x8 xr2 = *(const bf16x8*)(xsrc + 16);
    bf16x8 xr3 = *(const bf16x8*)(xsrc + 24);

    for (int k0 = 0; k0 < D_MODEL; k0 += 64) {
        __syncthreads();
        *(bf16x8*)&Ws[wrow][wcol]   = wr0;
        *(bf16x8*)&Ws[wrow][wcol+8] = wr1;
        *(bf16x8*)&Xs[xrow][xcol]    = xr0;
        *(bf16x8*)&Xs[xrow][xcol+8]  = xr1;
        *(bf16x8*)&Xs[xrow][xcol+16] = xr2;
        *(bf16x8*)&Xs[xrow][xcol+24] = xr3;
        __syncthreads();
        if (k0 + 64 < D_MODEL) {
            int kn = k0 + 64;
            wr0 = *(const bf16x8*)(wsrc + kn);
            wr1 = *(const bf16x8*)(wsrc + kn + 8);
            xr0 = *(const bf16x8*)(xsrc + kn);
            xr1 = *(const bf16x8*)(xsrc + kn + 8);
            xr2 = *(const bf16x8*)(xsrc + kn + 16);
            xr3 = *(const bf16x8*)(xsrc + kn + 24);
        }
        for (int kf = 0; kf < 2; kf++) {
            bf16x8 af[4], bx[2];
            for (int fi = 0; fi < 4; fi++)
                af[fi] = *(const bf16x8*)&Ws[fi*16 + l15][kf*32 + quad*8];
            for (int mj = 0; mj < 2; mj++)
                bx[mj] = *(const bf16x8*)&Xs[w*32 + mj*16 + l15][kf*32 + quad*8];
            for (int fi = 0; fi < 4; fi++)
                for (int mj = 0; mj < 2; mj++)
                    acc[fi][mj] = __builtin_amdgcn_mfma_f32_16x16x32_bf16(af[fi], bx[mj], acc[fi][mj], 0, 0, 0);
        }
    }

    // lane holds C^T[f = f0 + fi*16 + quad*4 + r][m = m0 + w*32 + mj*16 + l15]
    int mat = f0 >> 9;                 // uniform per block
    int h = (f0 >> 6) & 7;
    int b = m0 >> 11;
    int nb = m0 & 2047;
    size_t bho = (size_t)(b*NHEAD + h);
    float4 bs4[4];
    for (int fi = 0; fi < 4; fi++)
        bs4[fi] = *(const float4*)(bias + f0 + fi*16 + quad*4);

    if (mat < 2) {
        bf16* dst = (mat == 0) ? qb : kb;
        float sc = (mat == 0) ? (0.125f * LOG2E) : 1.0f;
        for (int fi = 0; fi < 4; fi++) {
            for (int mj = 0; mj < 2; mj++) {
                int n = nb + w*32 + mj*16 + l15;
                bf16x4 pv;
                pv[0] = (bf16)((acc[fi][mj][0] + bs4[fi].x) * sc);
                pv[1] = (bf16)((acc[fi][mj][1] + bs4[fi].y) * sc);
                pv[2] = (bf16)((acc[fi][mj][2] + bs4[fi].z) * sc);
                pv[3] = (bf16)((acc[fi][mj][3] + bs4[fi].w) * sc);
                *(bf16x4*)(dst + (bho*NN + n)*HD + fi*16 + quad*4) = pv;
            }
        }
    } else {
        __syncthreads();
        bf16* Vt = smem;                       // [64][136]
        for (int fi = 0; fi < 4; fi++) {
            int d = fi*16 + quad*4;
            for (int mj = 0; mj < 2; mj++) {
                int mlc = w*32 + mj*16 + l15;
                Vt[(d+0)*136 + mlc] = (bf16)(acc[fi][mj][0] + bs4[fi].x);
                Vt[(d+1)*136 + mlc] = (bf16)(acc[fi][mj][1] + bs4[fi].y);
                Vt[(d+2)*136 + mlc] = (bf16)(acc[fi][mj][2] + bs4[fi].z);
                Vt[(d+3)*136 + mlc] = (bf16)(acc[fi][mj][3] + bs4[fi].w);
            }
        }
        __syncthreads();
        int d = t >> 2, mc = (t & 3) * 32;
        bf16* gdst = vtb + (bho*HD + d)*NN + nb + mc;
        for (int c = 0; c < 4; c++)
            *(bf16x8*)(gdst + c*8) = *(const bf16x8*)&Vt[d*136 + mc + c*8];
    }
}

// ---------------- kernel 3: flash attention, S^T + O^T, log2 softmax ----------------
// grid = 16 bh * 32 qt * KSPLIT. 256 thr / 4 waves; lane l15 owns one q-row.
// Q pre-scaled by 0.125*log2e; cp pre-scaled by log2e; mask scaled by log2e at bias build.
template<int KSPLIT>
__global__ __launch_bounds__(256, 5) void attn_t(const bf16* __restrict__ qb,
                                                 const bf16* __restrict__ kb,
                                                 const bf16* __restrict__ vtb,
                                                 const float* __restrict__ maskf,
                                                 const float* __restrict__ cp,
                                                 float* __restrict__ op,
                                                 float* __restrict__ ml,
                                                 float* __restrict__ out) {
    constexpr int NKEYS = NN / KSPLIT;
    constexpr int NTILES = NKEYS / 64;
    __shared__ bf16 Ks[64][72];
    __shared__ bf16 Vts[64][72];
    __shared__ bf16 Ps[64][72];
    __shared__ float Cs[NKEYS];
    int t = threadIdx.x;
    int w = t >> 6, lane = t & 63;
    int quad = lane >> 4, l15 = lane & 15;
    int blk = blockIdx.x;
    int bh = blk & 15;
    int rest = blk >> 4;
    int qt = rest & 31, kp = rest >> 5;
    int q0 = qt * 64;
    int kbase = kp * NKEYS;
    size_t bhoff = (size_t)bh * (NN * HD);

    bf16x8 aq0, aq1;
    {
        const bf16* qp = qb + bhoff + (size_t)(q0 + w*16 + l15)*HD + quad*8;
        aq0 = *(const bf16x8*)(qp);
        aq1 = *(const bf16x8*)(qp + 32);
    }

    float m_i = -1e30f, l_i = 0.f;
    floatx4 o[4] = {};                 // O^T[d = dj*16+quad*4+r][q = w*16+l15]
    int qrow = q0 + w*16 + l15;
    const float* mrow = maskf + (size_t)qrow * NN;
    const float* cpb = cp + (size_t)bh * NN;
    int srow = t >> 2, scol = (t & 3) * 16;

    for (int i = t; i < NKEYS; i += 256) Cs[i] = cpb[kbase + i];
    __syncthreads();

    // prefetch tile 0
    bf16x8 kr0, kr1, vr0, vr1;
    float4 bias4[4];
    {
        const bf16* ks = kb + bhoff + (size_t)(kbase + srow)*HD + scol;
        kr0 = *(const bf16x8*)ks; kr1 = *(const bf16x8*)(ks + 8);
        const bf16* vs = vtb + bhoff + (size_t)srow*NN + kbase + scol;
        vr0 = *(const bf16x8*)vs; vr1 = *(const bf16x8*)(vs + 8);
        for (int j = 0; j < 4; j++) {
            float4 mv = *(const float4*)(mrow + kbase + j*16 + quad*4);
            float4 cv = *(const float4*)&Cs[j*16 + quad*4];
            bias4[j].x = fmaf(mv.x, LOG2E, -cv.x);
            bias4[j].y = fmaf(mv.y, LOG2E, -cv.y);
            bias4[j].z = fmaf(mv.z, LOG2E, -cv.z);
            bias4[j].w = fmaf(mv.w, LOG2E, -cv.w);
        }
    }

    for (int kt = 0; kt < NTILES; kt++) {
        __syncthreads();
        *(bf16x8*)&Ks[srow][scol]      = kr0;
        *(bf16x8*)&Ks[srow][scol + 8]  = kr1;
        *(bf16x8*)&Vts[srow][scol]     = vr0;
        *(bf16x8*)&Vts[srow][scol + 8] = vr1;
        __syncthreads();

        float4 mn4[4];
        bool more = (kt + 1 < NTILES);
        if (more) {
            int kn = kbase + (kt+1)*64;
            const bf16* ks = kb + bhoff + (size_t)(kn + srow)*HD + scol;
            kr0 = *(const bf16x8*)ks; kr1 = *(const bf16x8*)(ks + 8);
            const bf16* vs = vtb + bhoff + (size_t)srow*NN + kn + scol;
            vr0 = *(const bf16x8*)vs; vr1 = *(const bf16x8*)(vs + 8);
            for (int j = 0; j < 4; j++)
                mn4[j] = *(const float4*)(mrow + kn + j*16 + quad*4);
        }

        // S^T = K*Q'^T + bias (log2-domain), via accumulator init
        floatx4 s[4];
        for (int j = 0; j < 4; j++) {
            s[j][0] = bias4[j].x; s[j][1] = bias4[j].y;
            s[j][2] = bias4[j].z; s[j][3] = bias4[j].w;
            bf16x8 ka0 = *(const bf16x8*)&Ks[j*16 + l15][quad*8];
            bf16x8 ka1 = *(const bf16x8*)&Ks[j*16 + l15][32 + quad*8];
            s[j] = __builtin_amdgcn_mfma_f32_16x16x32_bf16(ka0, aq0, s[j], 0, 0, 0);
            s[j] = __builtin_amdgcn_mfma_f32_16x16x32_bf16(ka1, aq1, s[j], 0, 0, 0);
        }

        // softmax (base 2) for q=l15: in-lane tree + 2 shfl
        float mx = s[0][0];
        for (int j = 0; j < 4; j++)
            for (int r = 0; r < 4; r++) mx = fmaxf(mx, s[j][r]);
        mx = fmaxf(mx, __shfl_xor(mx, 16));
        mx = fmaxf(mx, __shfl_xor(mx, 32));
        float mnew = fmaxf(m_i, mx);
        float al = exp2_fast(m_i - mnew);
        float rs = 0.f;
        for (int j = 0; j < 4; j++)
            for (int r = 0; r < 4; r++) {
                float p = exp2_fast(s[j][r] - mnew);
                s[j][r] = p;
                rs += p;
            }
        rs += __shfl_xor(rs, 16);
        rs += __shfl_xor(rs, 32);
        l_i = l_i * al + rs;
        m_i = mnew;

        // rescale O^T: per-lane al (same q=l15) — no shuffles
        for (int dj = 0; dj < 4; dj++)
            for (int r = 0; r < 4; r++) o[dj][r] *= al;

        // P^T -> Ps[q][key] (b64 writes; same-wave rows, in-order LDS)
        for (int j = 0; j < 4; j++) {
            bf16x4 pv;
            pv[0] = (bf16)s[j][0]; pv[1] = (bf16)s[j][1];
            pv[2] = (bf16)s[j][2]; pv[3] = (bf16)s[j][3];
            *(bf16x4*)&Ps[w*16 + l15][j*16 + quad*4] = pv;
        }

        // O^T += V^T * P^T  (A = Vt rows, B = P rows — operandswap keeps O transposed)
        for (int kf2 = 0; kf2 < 2; kf2++) {
            bf16x8 ap = *(const bf16x8*)&Ps[w*16 + l15][kf2*32 + quad*8];
            for (int dj = 0; dj < 4; dj++) {
                bf16x8 bv = *(const bf16x8*)&Vts[dj*16 + l15][kf2*32 + quad*8];
                o[dj] = __builtin_amdgcn_mfma_f32_16x16x32_bf16(bv, ap, o[dj], 0, 0, 0);
            }
        }

        if (more) {
            int kn_loc = (kt+1)*64;
            for (int j = 0; j < 4; j++) {
                float4 cv = *(const float4*)&Cs[kn_loc + j*16 + quad*4];
                bias4[j].x = fmaf(mn4[j].x, LOG2E, -cv.x);
                bias4[j].y = fmaf(mn4[j].y, LOG2E, -cv.y);
                bias4[j].z = fmaf(mn4[j].z, LOG2E, -cv.z);
                bias4[j].w = fmaf(mn4[j].w, LOG2E, -cv.w);
            }
        }
    }

    int b = bh >> 3, h = bh & 7;
    if (KSPLIT == 1) {
        float inv = 1.0f / l_i;
        for (int dj = 0; dj < 4; dj++) {
            floatx4 res;
            for (int r = 0; r < 4; r++) res[r] = o[dj][r] * inv;
            *(floatx4*)(out + ((size_t)(b*NN + qrow))*D_MODEL + h*HD + dj*16 + quad*4) = res;
        }
    } else {
        size_t pbase = (size_t)kp * BH * NN;
        float* dst = op + (pbase + (size_t)bh*NN + qrow)*HD + quad*4;
        for (int dj = 0; dj < 4; dj++)
            *(floatx4*)(dst + dj*16) = o[dj];
        if (quad == 0) {
            float2 v; v.x = m_i; v.y = l_i;
            *(float2*)(ml + (pbase + (size_t)bh*NN + qrow)*2) = v;
        }
    }
}

// ---------------- kernel 4: combine ksplit partials (m in log2 domain) ----------------
__global__ __launch_bounds__(256) void combineN(const float* __restrict__ op,
                                                const float* __restrict__ ml,
                                                float* __restrict__ out,
                                                int ksplit) {
    int idx = blockIdx.x * 256 + threadIdx.x;    // 32768 rows * 16 chunks
    int row = idx >> 4, c4 = (idx & 15) * 4;
    float mstar = -1e30f;
    for (int kp = 0; kp < ksplit; kp++)
        mstar = fmaxf(mstar, ml[((size_t)kp*BH*NN + row)*2]);
    float denom = 0.f;
    float ax = 0.f, ay = 0.f, az = 0.f, aw = 0.f;
    for (int kp = 0; kp < ksplit; kp++) {
        float2 m2 = *(const float2*)(ml + ((size_t)kp*BH*NN + row)*2);
        float wgt = exp2_fast(m2.x - mstar);
        denom += wgt * m2.y;
        float4 ov = *(const float4*)(op + ((size_t)kp*BH*NN + row)*HD + c4);
        ax += wgt*ov.x; ay += wgt*ov.y; az += wgt*ov.z; aw += wgt*ov.w;
    }
    float inv = 1.0f / denom;
    int bh = row >> 11, q = row & 2047;
    int b = bh >> 3, h = bh & 7;
    float4 res; res.x = ax*inv; res.y = ay*inv; res.z = az*inv; res.w = aw*inv;
    *(float4*)(out + ((size_t)(b*NN + q))*D_MODEL + h*HD + c4) = res;
}

extern "C" void kernel_launch(void* const* d_in, const int* in_sizes, int n_in,
                              void* d_out, int out_size, void* d_ws, size_t ws_size,
                              hipStream_t stream) {
    const float* x      = (const float*)d_in[0];
    const float* coords = (const float*)d_in[1];
    const float* amask  = (const float*)d_in[2];
    const float* qkv_w  = (const float*)d_in[3];
    const float* qkv_b  = (const float*)d_in[4];
    const float* rw     = (const float*)d_in[5];
    float* out = (float*)d_out;

    char* ws = (char*)d_ws;
    float* cp  = (float*)(ws + 0);          // 131072
    bf16*  xb  = (bf16*) (ws + 131072);     // 4194304
    bf16*  wb  = (bf16*) (ws + 4325376);    // 1572864
    bf16*  qb  = (bf16*) (ws + 5898240);    // 4194304
    bf16*  kb  = (bf16*) (ws + 10092544);   // 4194304
    bf16*  vtb = (bf16*) (ws + 14286848);   // 4194304
    float* op  = (float*)(ws + 18481152);   // split*8388608

    int split = 1;
    if (ws_size >= 53084160u)      split = 4;
    else if (ws_size >= 35782656u) split = 2;
    float* ml = (float*)(ws + 18481152 + (size_t)split*8388608);

    convxw   <<<dim3(2832), dim3(256), 0, stream>>>(x, qkv_w, xb, wb, coords, rw, cp);
    qkv_gemm <<<dim3(768),  dim3(256), 0, stream>>>(xb, wb, qkv_b, qb, kb, vtb);
    if (split == 4)
        attn_t<4><<<dim3(2048), dim3(256), 0, stream>>>(qb, kb, vtb, amask, cp, op, ml, out);
    else if (split == 2)
        attn_t<2><<<dim3(1024), dim3(256), 0, stream>>>(qb, kb, vtb, amask, cp, op, ml, out);
    else
        attn_t<1><<<dim3(512),  dim3(256), 0, stream>>>(qb, kb, vtb, amask, cp, op, ml, out);
    if (split > 1)
        combineN<<<dim3(2048), dim3(256), 0, stream>>>(op, ml, out, split);
}

// Round 6
// 153.779 us; speedup vs baseline: 1.0016x; 1.0016x over previous
//
#include <hip/hip_runtime.h>
#include <hip/hip_bf16.h>

typedef __bf16 bf16;
typedef __bf16 bf16x4 __attribute__((ext_vector_type(4)));
typedef __bf16 bf16x8 __attribute__((ext_vector_type(8)));
typedef float floatx4 __attribute__((ext_vector_type(4)));

#define D_MODEL 512
#define NHEAD 8
#define HD 64
#define NB 2
#define NN 2048
#define BH (NB*NHEAD)
#define LOG2E 1.4426950408889634f

__device__ __forceinline__ float exp2_fast(float x) {
    float r;
    asm("v_exp_f32 %0, %1" : "=v"(r) : "v"(x));
    return r;
}

template<typename MT> struct MaskVec;
template<> struct MaskVec<bf16> {
    using V = bf16x4;
    static __device__ __forceinline__ float4 tof4(V v) {   // pre-scaled by LOG2E at conv
        return make_float4((float)v[0], (float)v[1], (float)v[2], (float)v[3]);
    }
};
template<> struct MaskVec<float> {
    using V = float4;
    static __device__ __forceinline__ float4 tof4(V v) {
        return make_float4(v.x*LOG2E, v.y*LOG2E, v.z*LOG2E, v.w*LOG2E);
    }
};

// ---------------- kernel 0: conversions + coordproj ----------------
// blocks [0,2048): x f32->bf16 ; [2048,2816): w ; [2816,2832): coordproj ;
// [2832,6928): mask -> bf16 scaled by LOG2E (only launched when ws permits)
__global__ __launch_bounds__(256) void convxw(const float* __restrict__ x,
                                              const float* __restrict__ w,
                                              bf16* __restrict__ xb,
                                              bf16* __restrict__ wb,
                                              const float* __restrict__ coords,
                                              const float* __restrict__ rw,
                                              float* __restrict__ cp,
                                              const float* __restrict__ maskf,
                                              bf16* __restrict__ mb) {
    int blk = blockIdx.x;
    if (blk < 2816) {
        int idx = blk * 256 + threadIdx.x;
        const float* src; bf16* dst; int i4;
        if (idx < 524288) { src = x; dst = xb; i4 = idx; }
        else              { src = w; dst = wb; i4 = idx - 524288; }
        float4 v = *(const float4*)(src + (size_t)i4*4);
        bf16x4 o; o[0] = (bf16)v.x; o[1] = (bf16)v.y; o[2] = (bf16)v.z; o[3] = (bf16)v.w;
        *(bf16x4*)(dst + (size_t)i4*4) = o;
    } else if (blk < 2832) {
        int idx = (blk - 2816) * 256 + threadIdx.x;   // (b,n)
        int b = idx >> 11, n = idx & 2047;
        float c0 = coords[idx*3 + 0];
        float c1 = coords[idx*3 + 1];
        float c2 = coords[idx*3 + 2];
        for (int h = 0; h < NHEAD; h++) {
            float v = c0*rw[h*3+0] + c1*rw[h*3+1] + c2*rw[h*3+2];
            cp[(size_t)(b*NHEAD + h)*NN + n] = v * LOG2E;
        }
    } else {
        int i4 = (blk - 2832) * 256 + threadIdx.x;    // 1048576 float4s
        float4 v = *(const float4*)(maskf + (size_t)i4*4);
        bf16x4 o;
        o[0] = (bf16)(v.x * LOG2E); o[1] = (bf16)(v.y * LOG2E);
        o[2] = (bf16)(v.z * LOG2E); o[3] = (bf16)(v.w * LOG2E);
        *(bf16x4*)(mb + (size_t)i4*4) = o;
    }
}

// ---------------- kernel 2: QKV GEMM, C^T = W * X^T, register-prefetched ----------------
__global__ __launch_bounds__(256, 4) void qkv_gemm(const bf16* __restrict__ xb,
                                                   const bf16* __restrict__ wb,
                                                   const float* __restrict__ bias,
                                                   bf16* __restrict__ qb,
                                                   bf16* __restrict__ kb,
                                                   bf16* __restrict__ vtb) {
    __shared__ bf16 smem[64*72 + 128*72];
    bf16 (*Ws)[72] = (bf16(*)[72])smem;
    bf16 (*Xs)[72] = (bf16(*)[72])(smem + 64*72);
    int t = threadIdx.x;
    int w = t >> 6, lane = t & 63, quad = lane >> 4, l15 = lane & 15;
    int blk = blockIdx.x;
    int bf = blk % 24, bm = blk / 24;
    int f0 = bf * 64, m0 = bm * 128;

    floatx4 acc[4][2] = {};
    int wrow = t >> 2, wcol = (t & 3) * 16;
    int xrow = t >> 1, xcol = (t & 1) * 32;

    const bf16* wsrc = wb + (size_t)(f0 + wrow)*D_MODEL + wcol;
    const bf16* xsrc = xb + (size_t)(m0 + xrow)*D_MODEL + xcol;

    bf16x8 wr0 = *(const bf16x8*)wsrc;
    bf16x8 wr1 = *(const bf16x8*)(wsrc + 8);
    bf16x8 xr0 = *(const bf16x8*)xsrc;
    bf16x8 xr1 = *(const bf16x8*)(xsrc + 8);
    bf16x8 xr2 = *(const bf16x8*)(xsrc + 16);
    bf16x8 xr3 = *(const bf16x8*)(xsrc + 24);

    for (int k0 = 0; k0 < D_MODEL; k0 += 64) {
        __syncthreads();
        *(bf16x8*)&Ws[wrow][wcol]   = wr0;
        *(bf16x8*)&Ws[wrow][wcol+8] = wr1;
        *(bf16x8*)&Xs[xrow][xcol]    = xr0;
        *(bf16x8*)&Xs[xrow][xcol+8]  = xr1;
        *(bf16x8*)&Xs[xrow][xcol+16] = xr2;
        *(bf16x8*)&Xs[xrow][xcol+24] = xr3;
        __syncthreads();
        if (k0 + 64 < D_MODEL) {
            int kn = k0 + 64;
            wr0 = *(const bf16x8*)(wsrc + kn);
            wr1 = *(const bf16x8*)(wsrc + kn + 8);
            xr0 = *(const bf16x8*)(xsrc + kn);
            xr1 = *(const bf16x8*)(xsrc + kn + 8);
            xr2 = *(const bf16x8*)(xsrc + kn + 16);
            xr3 = *(const bf16x8*)(xsrc + kn + 24);
        }
        for (int kf = 0; kf < 2; kf++) {
            bf16x8 af[4], bx[2];
            for (int fi = 0; fi < 4; fi++)
                af[fi] = *(const bf16x8*)&Ws[fi*16 + l15][kf*32 + quad*8];
            for (int mj = 0; mj < 2; mj++)
                bx[mj] = *(const bf16x8*)&Xs[w*32 + mj*16 + l15][kf*32 + quad*8];
            for (int fi = 0; fi < 4; fi++)
                for (int mj = 0; mj < 2; mj++)
                    acc[fi][mj] = __builtin_amdgcn_mfma_f32_16x16x32_bf16(af[fi], bx[mj], acc[fi][mj], 0, 0, 0);
        }
    }

    int mat = f0 >> 9;
    int h = (f0 >> 6) & 7;
    int b = m0 >> 11;
    int nb = m0 & 2047;
    size_t bho = (size_t)(b*NHEAD + h);
    float4 bs4[4];
    for (int fi = 0; fi < 4; fi++)
        bs4[fi] = *(const float4*)(bias + f0 + fi*16 + quad*4);

    if (mat < 2) {
        bf16* dst = (mat == 0) ? qb : kb;
        float sc = (mat == 0) ? (0.125f * LOG2E) : 1.0f;
        for (int fi = 0; fi < 4; fi++) {
            for (int mj = 0; mj < 2; mj++) {
                int n = nb + w*32 + mj*16 + l15;
                bf16x4 pv;
                pv[0] = (bf16)((acc[fi][mj][0] + bs4[fi].x) * sc);
                pv[1] = (bf16)((acc[fi][mj][1] + bs4[fi].y) * sc);
                pv[2] = (bf16)((acc[fi][mj][2] + bs4[fi].z) * sc);
                pv[3] = (bf16)((acc[fi][mj][3] + bs4[fi].w) * sc);
                *(bf16x4*)(dst + (bho*NN + n)*HD + fi*16 + quad*4) = pv;
            }
        }
    } else {
        __syncthreads();
        bf16* Vt = smem;                       // [64][136]
        for (int fi = 0; fi < 4; fi++) {
            int d = fi*16 + quad*4;
            for (int mj = 0; mj < 2; mj++) {
                int mlc = w*32 + mj*16 + l15;
                Vt[(d+0)*136 + mlc] = (bf16)(acc[fi][mj][0] + bs4[fi].x);
                Vt[(d+1)*136 + mlc] = (bf16)(acc[fi][mj][1] + bs4[fi].y);
                Vt[(d+2)*136 + mlc] = (bf16)(acc[fi][mj][2] + bs4[fi].z);
                Vt[(d+3)*136 + mlc] = (bf16)(acc[fi][mj][3] + bs4[fi].w);
            }
        }
        __syncthreads();
        int d = t >> 2, mc = (t & 3) * 32;
        bf16* gdst = vtb + (bho*HD + d)*NN + nb + mc;
        for (int c = 0; c < 4; c++)
            *(bf16x8*)(gdst + c*8) = *(const bf16x8*)&Vt[d*136 + mc + c*8];
    }
}

// ---------------- kernel 3: flash attention, 2 q-subtiles/wave ----------------
// grid = 16 bh * 16 qt(128 rows) * KSPLIT. 4 waves; wave owns 32 q-rows (2 subtiles of 16).
// K/V-frag LDS reads reused across subtiles -> ~1.7x less LDS traffic.
template<int KSPLIT, typename MT>
__global__ __launch_bounds__(256, 4) void attn_t(const bf16* __restrict__ qb,
                                                 const bf16* __restrict__ kb,
                                                 const bf16* __restrict__ vtb,
                                                 const MT* __restrict__ maskb,
                                                 const float* __restrict__ cp,
                                                 float* __restrict__ op,
                                                 float* __restrict__ ml,
                                                 float* __restrict__ out) {
    constexpr int NKEYS = NN / KSPLIT;
    constexpr int NTILES = NKEYS / 64;
    using MV = typename MaskVec<MT>::V;
    __shared__ bf16 Ks[64][72];
    __shared__ bf16 Vts[64][72];
    __shared__ bf16 Ps[128][72];
    __shared__ float Cs[NKEYS];
    int t = threadIdx.x;
    int w = t >> 6, lane = t & 63;
    int quad = lane >> 4, l15 = lane & 15;
    int blk = blockIdx.x;
    int bh = blk & 15;
    int rest = blk >> 4;
    int qt = rest & 15, kp = rest >> 4;
    int q0 = qt * 128;
    int kbase = kp * NKEYS;
    size_t bhoff = (size_t)bh * (NN * HD);

    bf16x8 aq[2][2];
    for (int sub = 0; sub < 2; sub++) {
        const bf16* qp = qb + bhoff + (size_t)(q0 + sub*64 + w*16 + l15)*HD + quad*8;
        aq[sub][0] = *(const bf16x8*)(qp);
        aq[sub][1] = *(const bf16x8*)(qp + 32);
    }

    float m_i[2] = {-1e30f, -1e30f}, l_i[2] = {0.f, 0.f};
    floatx4 o[2][4] = {};              // O^T per sub
    int qrow0 = q0 + w*16 + l15;
    const MT* mrow0 = maskb + (size_t)qrow0 * NN;
    const MT* mrow1 = mrow0 + (size_t)64 * NN;
    const float* cpb = cp + (size_t)bh * NN;
    int srow = t >> 2, scol = (t & 3) * 16;

    for (int i = t; i < NKEYS; i += 256) Cs[i] = cpb[kbase + i];
    // (Cs reads happen only after the second barrier of iteration 0)

    // prefetch tile 0
    bf16x8 kr0, kr1, vr0, vr1;
    MV mm[2][4];
    {
        const bf16* ks = kb + bhoff + (size_t)(kbase + srow)*HD + scol;
        kr0 = *(const bf16x8*)ks; kr1 = *(const bf16x8*)(ks + 8);
        const bf16* vs = vtb + bhoff + (size_t)srow*NN + kbase + scol;
        vr0 = *(const bf16x8*)vs; vr1 = *(const bf16x8*)(vs + 8);
        for (int j = 0; j < 4; j++) {
            mm[0][j] = *(const MV*)(mrow0 + kbase + j*16 + quad*4);
            mm[1][j] = *(const MV*)(mrow1 + kbase + j*16 + quad*4);
        }
    }

    for (int kt = 0; kt < NTILES; kt++) {
        __syncthreads();
        *(bf16x8*)&Ks[srow][scol]      = kr0;
        *(bf16x8*)&Ks[srow][scol + 8]  = kr1;
        *(bf16x8*)&Vts[srow][scol]     = vr0;
        *(bf16x8*)&Vts[srow][scol + 8] = vr1;
        __syncthreads();

        // S init = mask*log2e - cp (bias as MFMA C-init), from CURRENT mm
        floatx4 s[2][4];
        int kloc = kt * 64;
        for (int sub = 0; sub < 2; sub++)
            for (int j = 0; j < 4; j++) {
                float4 mf = MaskVec<MT>::tof4(mm[sub][j]);
                float4 cv = *(const float4*)&Cs[kloc + j*16 + quad*4];
                s[sub][j][0] = mf.x - cv.x;
                s[sub][j][1] = mf.y - cv.y;
                s[sub][j][2] = mf.z - cv.z;
                s[sub][j][3] = mf.w - cv.w;
            }

        // prefetch next tile
        bool more = (kt + 1 < NTILES);
        if (more) {
            int kn = kbase + (kt+1)*64;
            const bf16* ks = kb + bhoff + (size_t)(kn + srow)*HD + scol;
            kr0 = *(const bf16x8*)ks; kr1 = *(const bf16x8*)(ks + 8);
            const bf16* vs = vtb + bhoff + (size_t)srow*NN + kn + scol;
            vr0 = *(const bf16x8*)vs; vr1 = *(const bf16x8*)(vs + 8);
            for (int j = 0; j < 4; j++) {
                mm[0][j] = *(const MV*)(mrow0 + kn + j*16 + quad*4);
                mm[1][j] = *(const MV*)(mrow1 + kn + j*16 + quad*4);
            }
        }

        // S^T = K*Q'^T: K-frags reused across both q-subtiles
        for (int j = 0; j < 4; j++) {
            bf16x8 ka0 = *(const bf16x8*)&Ks[j*16 + l15][quad*8];
            bf16x8 ka1 = *(const bf16x8*)&Ks[j*16 + l15][32 + quad*8];
            s[0][j] = __builtin_amdgcn_mfma_f32_16x16x32_bf16(ka0, aq[0][0], s[0][j], 0, 0, 0);
            s[1][j] = __builtin_amdgcn_mfma_f32_16x16x32_bf16(ka0, aq[1][0], s[1][j], 0, 0, 0);
            s[0][j] = __builtin_amdgcn_mfma_f32_16x16x32_bf16(ka1, aq[0][1], s[0][j], 0, 0, 0);
            s[1][j] = __builtin_amdgcn_mfma_f32_16x16x32_bf16(ka1, aq[1][1], s[1][j], 0, 0, 0);
        }

        // softmax (base 2), two independent chains
        for (int sub = 0; sub < 2; sub++) {
            float mx = s[sub][0][0];
            for (int j = 0; j < 4; j++)
                for (int r = 0; r < 4; r++) mx = fmaxf(mx, s[sub][j][r]);
            mx = fmaxf(mx, __shfl_xor(mx, 16));
            mx = fmaxf(mx, __shfl_xor(mx, 32));
            float mnew = fmaxf(m_i[sub], mx);
            float al = exp2_fast(m_i[sub] - mnew);
            float rs = 0.f;
            for (int j = 0; j < 4; j++)
                for (int r = 0; r < 4; r++) {
                    float p = exp2_fast(s[sub][j][r] - mnew);
                    s[sub][j][r] = p;
                    rs += p;
                }
            rs += __shfl_xor(rs, 16);
            rs += __shfl_xor(rs, 32);
            l_i[sub] = l_i[sub] * al + rs;
            m_i[sub] = mnew;
            for (int dj = 0; dj < 4; dj++)
                for (int r = 0; r < 4; r++) o[sub][dj][r] *= al;
            // P^T -> Ps (b64; same-wave rows, in-order LDS)
            for (int j = 0; j < 4; j++) {
                bf16x4 pv;
                pv[0] = (bf16)s[sub][j][0]; pv[1] = (bf16)s[sub][j][1];
                pv[2] = (bf16)s[sub][j][2]; pv[3] = (bf16)s[sub][j][3];
                *(bf16x4*)&Ps[sub*64 + w*16 + l15][j*16 + quad*4] = pv;
            }
        }

        // O^T += V^T * P^T: V-frags reused across both q-subtiles
        for (int kf2 = 0; kf2 < 2; kf2++) {
            bf16x8 ap0 = *(const bf16x8*)&Ps[w*16 + l15][kf2*32 + quad*8];
            bf16x8 ap1 = *(const bf16x8*)&Ps[64 + w*16 + l15][kf2*32 + quad*8];
            for (int dj = 0; dj < 4; dj++) {
                bf16x8 bv = *(const bf16x8*)&Vts[dj*16 + l15][kf2*32 + quad*8];
                o[0][dj] = __builtin_amdgcn_mfma_f32_16x16x32_bf16(bv, ap0, o[0][dj], 0, 0, 0);
                o[1][dj] = __builtin_amdgcn_mfma_f32_16x16x32_bf16(bv, ap1, o[1][dj], 0, 0, 0);
            }
        }
    }

    int b = bh >> 3, h = bh & 7;
    for (int sub = 0; sub < 2; sub++) {
        int qr = q0 + sub*64 + w*16 + l15;
        if (KSPLIT == 1) {
            float inv = 1.0f / l_i[sub];
            for (int dj = 0; dj < 4; dj++) {
                floatx4 res;
                for (int r = 0; r < 4; r++) res[r] = o[sub][dj][r] * inv;
                *(floatx4*)(out + ((size_t)(b*NN + qr))*D_MODEL + h*HD + dj*16 + quad*4) = res;
            }
        } else {
            size_t pbase = (size_t)kp * BH * NN;
            float* dst = op + (pbase + (size_t)bh*NN + qr)*HD + quad*4;
            for (int dj = 0; dj < 4; dj++)
                *(floatx4*)(dst + dj*16) = o[sub][dj];
            if (quad == 0) {
                float2 v; v.x = m_i[sub]; v.y = l_i[sub];
                *(float2*)(ml + (pbase + (size_t)bh*NN + qr)*2) = v;
            }
        }
    }
}

// ---------------- kernel 4: combine ksplit partials (m in log2 domain) ----------------
__global__ __launch_bounds__(256) void combineN(const float* __restrict__ op,
                                                const float* __restrict__ ml,
                                                float* __restrict__ out,
                                                int ksplit) {
    int idx = blockIdx.x * 256 + threadIdx.x;    // 32768 rows * 16 chunks
    int row = idx >> 4, c4 = (idx & 15) * 4;
    float mstar = -1e30f;
    for (int kp = 0; kp < ksplit; kp++)
        mstar = fmaxf(mstar, ml[((size_t)kp*BH*NN + row)*2]);
    float denom = 0.f;
    float ax = 0.f, ay = 0.f, az = 0.f, aw = 0.f;
    for (int kp = 0; kp < ksplit; kp++) {
        float2 m2 = *(const float2*)(ml + ((size_t)kp*BH*NN + row)*2);
        float wgt = exp2_fast(m2.x - mstar);
        denom += wgt * m2.y;
        float4 ov = *(const float4*)(op + ((size_t)kp*BH*NN + row)*HD + c4);
        ax += wgt*ov.x; ay += wgt*ov.y; az += wgt*ov.z; aw += wgt*ov.w;
    }
    float inv = 1.0f / denom;
    int bh = row >> 11, q = row & 2047;
    int b = bh >> 3, h = bh & 7;
    float4 res; res.x = ax*inv; res.y = ay*inv; res.z = az*inv; res.w = aw*inv;
    *(float4*)(out + ((size_t)(b*NN + q))*D_MODEL + h*HD + c4) = res;
}

extern "C" void kernel_launch(void* const* d_in, const int* in_sizes, int n_in,
                              void* d_out, int out_size, void* d_ws, size_t ws_size,
                              hipStream_t stream) {
    const float* x      = (const float*)d_in[0];
    const float* coords = (const float*)d_in[1];
    const float* amask  = (const float*)d_in[2];
    const float* qkv_w  = (const float*)d_in[3];
    const float* qkv_b  = (const float*)d_in[4];
    const float* rw     = (const float*)d_in[5];
    float* out = (float*)d_out;

    char* ws = (char*)d_ws;
    float* cp  = (float*)(ws + 0);          // 131072
    bf16*  xb  = (bf16*) (ws + 131072);     // 4 MB
    bf16*  wb  = (bf16*) (ws + 4325376);    // 1.5 MB
    bf16*  qb  = (bf16*) (ws + 5898240);    // 4 MB
    bf16*  kb  = (bf16*) (ws + 10092544);   // 4 MB
    bf16*  vtb = (bf16*) (ws + 14286848);   // 4 MB   -> end 18481152
    bf16*  mb  = (bf16*) (ws + 18481152);   // 8 MB when mask-bf16 enabled

    int split; bool mbf;
    if      (ws_size >= 60948480u) { split = 4; mbf = true;  }
    else if (ws_size >= 53084160u) { split = 4; mbf = false; }
    else if (ws_size >= 44171264u) { split = 2; mbf = true;  }
    else if (ws_size >= 35782656u) { split = 2; mbf = false; }
    else                           { split = 1; mbf = false; }

    size_t opoff = mbf ? 26869760u : 18481152u;
    float* op = (float*)(ws + opoff);
    float* ml = (float*)(ws + opoff + (size_t)split*8388608);

    convxw<<<dim3(mbf ? 6928 : 2832), dim3(256), 0, stream>>>(
        x, qkv_w, xb, wb, coords, rw, cp, amask, mb);
    qkv_gemm<<<dim3(768), dim3(256), 0, stream>>>(xb, wb, qkv_b, qb, kb, vtb);

    if (split == 4) {
        if (mbf) attn_t<4, bf16 ><<<dim3(1024), dim3(256), 0, stream>>>(qb, kb, vtb, mb,    cp, op, ml, out);
        else     attn_t<4, float><<<dim3(1024), dim3(256), 0, stream>>>(qb, kb, vtb, amask, cp, op, ml, out);
    } else if (split == 2) {
        if (mbf) attn_t<2, bf16 ><<<dim3(512),  dim3(256), 0, stream>>>(qb, kb, vtb, mb,    cp, op, ml, out);
        else     attn_t<2, float><<<dim3(512),  dim3(256), 0, stream>>>(qb, kb, vtb, amask, cp, op, ml, out);
    } else {
        attn_t<1, float><<<dim3(256), dim3(256), 0, stream>>>(qb, kb, vtb, amask, cp, op, ml, out);
    }
    if (split > 1)
        combineN<<<dim3(2048), dim3(256), 0, stream>>>(op, ml, out, split);
}